// Round 7
// baseline (2877.864 us; speedup 1.0000x reference)
//
#include <hip/hip_runtime.h>
#include <hip/hip_bf16.h>

// Problem constants (fixed by reference)
#define NN 8192
#define NMASK 8191
#define IND 3000
#define H1 256
#define OUTD 64
#define GRID 768     // 3 blocks/CU on 256 CUs — co-resident (VGPR<=128 via launch_bounds, LDS ~19KB)
#define BLOCK 256

typedef __bf16 bf16x8 __attribute__((ext_vector_type(8)));
typedef float floatx4 __attribute__((ext_vector_type(4)));

__device__ __forceinline__ unsigned short f2b(float f) {
    __hip_bfloat16 h = __float2bfloat16(f);
    unsigned short u;
    __builtin_memcpy(&u, &h, 2);
    return u;
}

// ---------------- shared-memory union (max 18688 B) ----------------

union SMem {
    struct { unsigned short As[64 * 72]; unsigned short Bs[64 * 72]; } gemm;  // 18432
    float ttile[64][65];                                                       // 16640
    struct { int colS[64]; int pcolS[64]; float wS[64]; } agg;                 // 768
    struct { float sa[4][64]; float sc[4][64]; float sr[4]; } rd;              // 2064
    struct { float WdS[64][65]; float gS[4][64]; float gcS[4][64]; } bil;      // 18688
    int scan[256];
    int cnt[2];
};

// ---------------- device-scope grid barrier (bar[0]=arrive, bar[1]=generation) ----------------
// bar is zeroed by the pre-kernel hipMemsetAsync (stream-ordered, in-graph).

__device__ __forceinline__ void gridbar(int* bar) {
    __threadfence();   // make this block's stores visible device-wide (agent fence)
    __syncthreads();
    if (threadIdx.x == 0) {
        int g = __hip_atomic_load(&bar[1], __ATOMIC_RELAXED, __HIP_MEMORY_SCOPE_AGENT);
        int a = __hip_atomic_fetch_add(&bar[0], 1, __ATOMIC_ACQ_REL, __HIP_MEMORY_SCOPE_AGENT);
        if (a == GRID - 1) {
            __hip_atomic_store(&bar[0], 0, __ATOMIC_RELAXED, __HIP_MEMORY_SCOPE_AGENT);
            __hip_atomic_fetch_add(&bar[1], 1, __ATOMIC_RELEASE, __HIP_MEMORY_SCOPE_AGENT);
        } else {
            while (__hip_atomic_load(&bar[1], __ATOMIC_ACQUIRE, __HIP_MEMORY_SCOPE_AGENT) == g)
                __builtin_amdgcn_s_sleep(10);
        }
    }
    __syncthreads();
    __threadfence();   // acquire: observe other blocks' stores
}

// ---------------- GEMM tile: C[m0:m0+64, n0:n0+64] += A @ Bt^T ----------------
// A fp32 (AFP32=1) or bf16; Bt bf16 K-major; C fp32. BK=64, 4 waves.

template <int AFP32>
__device__ void gemm_tile(unsigned short* As, unsigned short* Bs,
                          const void* __restrict__ Araw, const __hip_bfloat16* __restrict__ Bt,
                          float* __restrict__ C, int m0, int n0, int N, int K) {
    int t = threadIdx.x;
    int lane = t & 63;
    int w = t >> 6;
    int srow = t >> 2;
    int kc = (t & 3) * 16;
    floatx4 acc0 = {0.f, 0.f, 0.f, 0.f}, acc1 = acc0, acc2 = acc0, acc3 = acc0;
    int msub = w * 16;
    int arow = msub + (lane & 15);
    int koff = (lane >> 4) * 8;
    int nlo = lane & 15;

    for (int k0 = 0; k0 < K; k0 += 64) {
        unsigned short a16[16] = {0};
        unsigned short b16[16] = {0};
#pragma unroll
        for (int h = 0; h < 2; ++h) {
            int kk = k0 + kc + h * 8;
            if (kk < K) {  // K % 8 == 0: in-bounds start => full chunk in bounds
                if (AFP32) {
                    const float* ap = (const float*)Araw + (size_t)(m0 + srow) * K + kk;
                    float4 f0 = *reinterpret_cast<const float4*>(ap);
                    float4 f1 = *reinterpret_cast<const float4*>(ap + 4);
                    a16[h * 8 + 0] = f2b(f0.x); a16[h * 8 + 1] = f2b(f0.y);
                    a16[h * 8 + 2] = f2b(f0.z); a16[h * 8 + 3] = f2b(f0.w);
                    a16[h * 8 + 4] = f2b(f1.x); a16[h * 8 + 5] = f2b(f1.y);
                    a16[h * 8 + 6] = f2b(f1.z); a16[h * 8 + 7] = f2b(f1.w);
                } else {
                    uint4 v = *reinterpret_cast<const uint4*>(
                        (const unsigned short*)Araw + (size_t)(m0 + srow) * K + kk);
                    __builtin_memcpy(&a16[h * 8], &v, 16);
                }
                uint4 bvv = *reinterpret_cast<const uint4*>(
                    (const unsigned short*)Bt + (size_t)(n0 + srow) * K + kk);
                __builtin_memcpy(&b16[h * 8], &bvv, 16);
            }
        }
        __syncthreads();
        *reinterpret_cast<uint4*>(&As[srow * 72 + kc]) = *reinterpret_cast<uint4*>(&a16[0]);
        *reinterpret_cast<uint4*>(&As[srow * 72 + kc + 8]) = *reinterpret_cast<uint4*>(&a16[8]);
        *reinterpret_cast<uint4*>(&Bs[srow * 72 + kc]) = *reinterpret_cast<uint4*>(&b16[0]);
        *reinterpret_cast<uint4*>(&Bs[srow * 72 + kc + 8]) = *reinterpret_cast<uint4*>(&b16[8]);
        __syncthreads();
        bf16x8 a0 = *reinterpret_cast<const bf16x8*>(&As[arow * 72 + koff]);
        bf16x8 a1 = *reinterpret_cast<const bf16x8*>(&As[arow * 72 + 32 + koff]);
#pragma unroll
        for (int j = 0; j < 4; ++j) {
            bf16x8 b0 = *reinterpret_cast<const bf16x8*>(&Bs[(j * 16 + nlo) * 72 + koff]);
            bf16x8 b1 = *reinterpret_cast<const bf16x8*>(&Bs[(j * 16 + nlo) * 72 + 32 + koff]);
            floatx4* ac = (j == 0) ? &acc0 : (j == 1) ? &acc1 : (j == 2) ? &acc2 : &acc3;
            *ac = __builtin_amdgcn_mfma_f32_16x16x32_bf16(a0, b0, *ac, 0, 0, 0);
            *ac = __builtin_amdgcn_mfma_f32_16x16x32_bf16(a1, b1, *ac, 0, 0, 0);
        }
    }
    // C/D layout: col = lane&15, row = (lane>>4)*4 + r  [verified m89/m91]
    int crow = msub + (lane >> 4) * 4;
    int ccol = lane & 15;
    floatx4 accs[4] = {acc0, acc1, acc2, acc3};
#pragma unroll
    for (int j = 0; j < 4; ++j) {
#pragma unroll
        for (int r = 0; r < 4; ++r) {
            C[(size_t)(m0 + crow + r) * N + (n0 + j * 16 + ccol)] = accs[j][r];
        }
    }
}

// ---------------- LDS-tiled fp32->bf16 transpose tile ----------------

__device__ void transpose_tile(SMem& sm, const float* __restrict__ in,
                               __hip_bfloat16* __restrict__ out, int R, int C,
                               int cx, int ry) {
    int c0 = cx * 64;
    int r0 = ry * 64;
    int t = threadIdx.x;
    int tc = t & 63;
    int tq = t >> 6;
    __syncthreads();
#pragma unroll
    for (int s = 0; s < 16; ++s) {
        int rr = tq + s * 4;
        int r = r0 + rr;
        sm.ttile[rr][tc] = (r < R) ? in[(size_t)r * C + c0 + tc] : 0.f;
    }
    __syncthreads();
#pragma unroll
    for (int s = 0; s < 16; ++s) {
        int cc = tq + s * 4;
        int r = r0 + tc;
        if (r < R) out[(size_t)(c0 + cc) * R + r] = __float2bfloat16(sm.ttile[tc][cc]);
    }
}

// ---------------- the megakernel ----------------

__global__ __launch_bounds__(256, 4) void k_mega(
    const float* __restrict__ gene, const float* __restrict__ mask,
    const float* __restrict__ W1, const float* __restrict__ b1,
    const float* __restrict__ W2, const float* __restrict__ b2,
    const float* __restrict__ Wd, const float* __restrict__ bd,
    const unsigned* __restrict__ eidx_raw, const unsigned* __restrict__ perm_raw,
    int* bar, int* deg, int* eidx32, int* perm32, int* row_ptr, int* cursor,
    float* dinv, int* col, __hip_bfloat16* W1t, __hip_bfloat16* W2t,
    float* xw1, __hip_bfloat16* h_all, float* hw_all, float* x1_all, float* g_all,
    float* out_x1, float* out_ret1, float* out_ret1c, int E, int n) {
    __shared__ __align__(16) SMem sm;
    const int tid = threadIdx.x;
    const int bid = blockIdx.x;

    // ---- S0a: index-width detection (per-block, redundant, from 256 sampled pairs) ----
    if (tid < 2) sm.cnt[tid] = 0;
    __syncthreads();
    {
        int c1 = (eidx_raw[2 * tid + 1] == 0u) ? 1 : 0;
        int c2 = (perm_raw[2 * tid + 1] == 0u) ? 1 : 0;
        if (c1) atomicAdd(&sm.cnt[0], 1);
        if (c2) atomicAdd(&sm.cnt[1], 1);
    }
    __syncthreads();
    const int f_e = sm.cnt[0] > 128;
    const int f_p = sm.cnt[1] > 128;

    // ---- S0b: normalize indices + fused degree count ----
    for (int i = bid * BLOCK + tid; i < 2 * E; i += GRID * BLOCK) {
        unsigned v = f_e ? eidx_raw[2 * (size_t)i] : eidx_raw[i];
        int x = (int)(v & (unsigned)NMASK);
        eidx32[i] = x;
        if (i >= E) atomicAdd(&deg[x], 1);
    }
    for (int i = bid * BLOCK + tid; i < n; i += GRID * BLOCK) {
        unsigned v = f_p ? perm_raw[2 * (size_t)i] : perm_raw[i];
        perm32[i] = (int)(v & (unsigned)NMASK);
    }
    gridbar(bar);

    // ---- S1: exclusive scan of degrees -> row_ptr/cursor/dinv (block 0 only) ----
    if (bid == 0) {
        int per = n / BLOCK;  // 32
        int base = tid * per;
        int s = 0;
        for (int u = 0; u < per; ++u) s += deg[base + u];
        sm.scan[tid] = s;
        __syncthreads();
        for (int off = 1; off < BLOCK; off <<= 1) {
            int v = (tid >= off) ? sm.scan[tid - off] : 0;
            __syncthreads();
            sm.scan[tid] += v;
            __syncthreads();
        }
        int run = tid ? sm.scan[tid - 1] : 0;
        for (int u = 0; u < per; ++u) {
            int i = base + u;
            int d = deg[i];
            row_ptr[i] = run;
            cursor[i] = run;
            dinv[i] = rsqrtf((float)(1 + d));
            run += d;
        }
        if (tid == BLOCK - 1) row_ptr[n] = run;
    }
    gridbar(bar);

    // ---- S2: CSR scatter + weight transposes ----
    for (int e = bid * BLOCK + tid; e < E; e += GRID * BLOCK) {
        int d = eidx32[E + e];
        int pos = atomicAdd(&cursor[d], 1);
        if (pos >= 0 && pos < E) col[pos] = eidx32[e];
    }
    if (bid < 188) {
        transpose_tile(sm, W1, W1t, IND, H1, bid & 3, bid >> 2);   // 4 x 47 tiles
    } else if (bid < 192) {
        transpose_tile(sm, W2, W2t, H1, OUTD, 0, bid - 188);       // 1 x 4 tiles
    }
    gridbar(bar);

    // ---- S3: GEMM1 xw1 = gene(fp32) @ W1t  (512 tiles on blocks 0..511) ----
    if (bid < 512) {
        int m0 = (bid & 127) * 64;
        int n0 = (bid >> 7) * 64;
        gemm_tile<1>(sm.gemm.As, sm.gemm.Bs, gene, W1t, xw1, m0, n0, H1, IND);
    }
    gridbar(bar);

    // ---- S4: conv1 aggregation (both graphs) -> h_all bf16 [2n x 256] ----
    for (int i = bid; i < n; i += GRID) {
        int c = tid;
        float di = dinv[i];
        int pi = perm32[i];
        float sw = di * di;
        float acc = sw * xw1[(size_t)i * H1 + c];
        float accc = sw * xw1[(size_t)pi * H1 + c];
        int s = row_ptr[i], e = row_ptr[i + 1];
        for (int base = s; base < e; base += 64) {
            int cnt2 = min(64, e - base);
            __syncthreads();
            if (c < cnt2) {
                int j = col[base + c];
                sm.agg.colS[c] = j;
                sm.agg.wS[c] = di * dinv[j];
                sm.agg.pcolS[c] = perm32[j];
            }
            __syncthreads();
#pragma unroll 4
            for (int u = 0; u < cnt2; ++u) {
                float wv = sm.agg.wS[u];
                acc += wv * xw1[(size_t)sm.agg.colS[u] * H1 + c];
                accc += wv * xw1[(size_t)sm.agg.pcolS[u] * H1 + c];
            }
        }
        float b = b1[c];
        h_all[(size_t)i * H1 + c] = __float2bfloat16(fmaxf(acc + b, 0.f));
        h_all[(size_t)(n + i) * H1 + c] = __float2bfloat16(fmaxf(accc + b, 0.f));
        __syncthreads();  // protect sm.agg reuse across row iterations
    }
    gridbar(bar);

    // ---- S5: GEMM2 hw_all = h_all(bf16) @ W2t  (256 tiles on blocks 0..255) ----
    if (bid < 256) {
        gemm_tile<0>(sm.gemm.As, sm.gemm.Bs, h_all, W2t, hw_all, bid * 64, 0, OUTD, H1);
    }
    gridbar(bar);

    // ---- S6: conv2 aggregation -> x1_all fp32 [2n x 64]; x1 to d_out ----
    {
        int lane = tid & 63;
        for (int i = bid * 4 + (tid >> 6); i < n; i += GRID * 4) {
            float di = dinv[i];
            float sw = di * di;
            float acc = sw * hw_all[(size_t)i * OUTD + lane];
            float accc = sw * hw_all[(size_t)(n + i) * OUTD + lane];
            int s = row_ptr[i], e = row_ptr[i + 1];
            for (int k = s; k < e; ++k) {
                int j = col[k];
                float wv = di * dinv[j];
                acc += wv * hw_all[(size_t)j * OUTD + lane];
                accc += wv * hw_all[(size_t)(n + j) * OUTD + lane];
            }
            float b = b2[lane];
            float v = fmaxf(acc + b, 0.f);
            float vc = fmaxf(accc + b, 0.f);
            x1_all[(size_t)i * OUTD + lane] = v;
            x1_all[(size_t)(n + i) * OUTD + lane] = vc;
            out_x1[(size_t)i * OUTD + lane] = v;
        }
    }
    gridbar(bar);

    // ---- S7: masked-mean readout + L2-normalize + sigmoid ----
    {
        int lane = tid & 63;
        int w = tid >> 6;
        for (int i = bid; i < n; i += GRID) {
            float acc = 0.f, accc = 0.f, rs = 0.f;
            const float* mrow = mask + (size_t)i * n;
            int qbase = w * (n >> 2);
            float4 q[8];
#pragma unroll
            for (int it = 0; it < 8; ++it)
                q[it] = *reinterpret_cast<const float4*>(mrow + qbase + it * 256 + lane * 4);
#pragma unroll
            for (int it = 0; it < 8; ++it) {
                bool nz = (q[it].x != 0.f) || (q[it].y != 0.f) || (q[it].z != 0.f) || (q[it].w != 0.f);
                unsigned long long bal = __ballot(nz);
                while (bal) {
                    int l = __builtin_ctzll(bal);
                    bal &= bal - 1;
                    float s0 = __shfl(q[it].x, l), s1 = __shfl(q[it].y, l);
                    float s2 = __shfl(q[it].z, l), s3 = __shfl(q[it].w, l);
                    int j0 = qbase + it * 256 + l * 4;
                    float sv[4] = {s0, s1, s2, s3};
#pragma unroll
                    for (int u = 0; u < 4; ++u) {
                        if (sv[u] != 0.f) {
                            float m = sv[u];
                            int j = j0 + u;
                            acc += m * x1_all[(size_t)j * OUTD + lane];
                            accc += m * x1_all[(size_t)(n + j) * OUTD + lane];
                            rs += m;
                        }
                    }
                }
            }
            __syncthreads();
            sm.rd.sa[w][lane] = acc;
            sm.rd.sc[w][lane] = accc;
            if (lane == 0) sm.rd.sr[w] = rs;
            __syncthreads();
            if (w == 0) {
                float tot = sm.rd.sa[0][lane] + sm.rd.sa[1][lane] + sm.rd.sa[2][lane] + sm.rd.sa[3][lane];
                float totc = sm.rd.sc[0][lane] + sm.rd.sc[1][lane] + sm.rd.sc[2][lane] + sm.rd.sc[3][lane];
                float rst = fmaxf(sm.rd.sr[0] + sm.rd.sr[1] + sm.rd.sr[2] + sm.rd.sr[3], 1e-20f);
                float g = tot / rst;
                float gc = totc / rst;
                float s1 = g * g, s2 = gc * gc;
#pragma unroll
                for (int off = 32; off; off >>= 1) {
                    s1 += __shfl_xor(s1, off);
                    s2 += __shfl_xor(s2, off);
                }
                float gn = g / fmaxf(sqrtf(s1), 1e-12f);
                float gnc = gc / fmaxf(sqrtf(s2), 1e-12f);
                g_all[(size_t)i * OUTD + lane] = 1.f / (1.f + __expf(-gn));
                g_all[(size_t)(n + i) * OUTD + lane] = 1.f / (1.f + __expf(-gnc));
            }
            __syncthreads();
        }
    }
    gridbar(bar);

    // ---- S8: bilinear discriminator -> ret1, ret1_c ----
    {
        __syncthreads();
        for (int u = tid; u < 64 * 64; u += BLOCK) sm.bil.WdS[u >> 6][u & 63] = Wd[u];
        __syncthreads();
        int lane = tid & 63;
        int q = tid >> 6;
        for (int i = bid * 4 + q; i < n; i += GRID * 4) {
            float g = g_all[(size_t)i * OUTD + lane];
            float gc = g_all[(size_t)(n + i) * OUTD + lane];
            sm.bil.gS[q][lane] = g;
            sm.bil.gcS[q][lane] = gc;
            __syncthreads();
            float tg = 0.f, tgc = 0.f;
#pragma unroll 8
            for (int j = 0; j < 64; ++j) {
                float wv = sm.bil.WdS[lane][j];
                tg += wv * sm.bil.gS[q][j];
                tgc += wv * sm.bil.gcS[q][j];
            }
            float x = x1_all[(size_t)i * OUTD + lane];
            float xc = x1_all[(size_t)(n + i) * OUTD + lane];
            float r0 = x * tg, r1 = xc * tg, r2 = xc * tgc, r3 = x * tgc;
#pragma unroll
            for (int off = 32; off; off >>= 1) {
                r0 += __shfl_down(r0, off);
                r1 += __shfl_down(r1, off);
                r2 += __shfl_down(r2, off);
                r3 += __shfl_down(r3, off);
            }
            if (lane == 0) {
                float b = bd[0];
                out_ret1[(size_t)i * 2 + 0] = r0 + b;
                out_ret1[(size_t)i * 2 + 1] = r1 + b;
                out_ret1c[(size_t)i * 2 + 0] = r2 + b;
                out_ret1c[(size_t)i * 2 + 1] = r3 + b;
            }
            __syncthreads();
        }
    }
}

// ---------------- ws-size probe ----------------

__global__ void k_probe(float code, float* out) {
    if (threadIdx.x == 0 && blockIdx.x == 0) out[0] = code;
}

// ---------------- host ----------------

extern "C" void kernel_launch(void* const* d_in, const int* in_sizes, int n_in,
                              void* d_out, int out_size, void* d_ws, size_t ws_size,
                              hipStream_t stream) {
    const float* gene = (const float*)d_in[0];
    const float* mask = (const float*)d_in[1];
    const float* W1 = (const float*)d_in[2];
    const float* b1 = (const float*)d_in[3];
    const float* W2 = (const float*)d_in[4];
    const float* b2 = (const float*)d_in[5];
    const float* Wd = (const float*)d_in[6];
    const float* bd = (const float*)d_in[7];
    const unsigned* eidx_raw = (const unsigned*)d_in[8];
    const unsigned* perm_raw = (const unsigned*)d_in[9];
    const int n = NN;
    const int E = in_sizes[8] / 2;  // 131072 logical edges

    // workspace carve-up (256B aligned); bar+deg adjacent for one memset
    char* base = (char*)d_ws;
    char* p = base;
    auto alloc = [&](size_t bytes) -> char* {
        char* r = p;
        p += (bytes + 255) & ~(size_t)255;
        return r;
    };
    int* bar = (int*)alloc(256);
    int* deg = (int*)alloc((size_t)n * 4);
    int* eidx32 = (int*)alloc((size_t)2 * E * 4);
    int* perm32 = (int*)alloc((size_t)n * 4);
    int* row_ptr = (int*)alloc((size_t)(n + 1) * 4);
    int* cursor = (int*)alloc((size_t)n * 4);
    float* dinv = (float*)alloc((size_t)n * 4);
    int* col = (int*)alloc((size_t)E * 4);
    __hip_bfloat16* W2t = (__hip_bfloat16*)alloc((size_t)H1 * OUTD * 2);
    __hip_bfloat16* W1t = (__hip_bfloat16*)alloc((size_t)IND * H1 * 2);
    float* xw1 = (float*)alloc((size_t)n * H1 * 4);                         // 8 MB
    __hip_bfloat16* h_all = (__hip_bfloat16*)alloc((size_t)2 * n * H1 * 2); // 8 MB
    size_t need = (size_t)(p - base);
    // aliases into dead buffers:
    float* hw_all = xw1;                         // xw1 dead after agg1
    float* x1_all = xw1 + (size_t)2 * n * OUTD;  // second half of xw1's 8 MB
    float* g_all = (float*)h_all;                // h_all dead after gemm2

    float* out_x1 = (float*)d_out;
    float* out_ret1 = out_x1 + (size_t)n * OUTD;
    float* out_ret1c = out_ret1 + (size_t)n * 2;

    if (ws_size < need) {
        k_probe<<<1, 64, 0, stream>>>(1000.f + (float)(ws_size >> 20), out_x1);
        return;
    }

    // zero barrier + degree counters (stream-ordered, graph-capturable)
    hipMemsetAsync(bar, 0, 256 + (size_t)n * 4, stream);

    k_mega<<<GRID, BLOCK, 0, stream>>>(
        gene, mask, W1, b1, W2, b2, Wd, bd, eidx_raw, perm_raw,
        bar, deg, eidx32, perm32, row_ptr, cursor, dinv, col, W1t, W2t,
        xw1, h_all, hw_all, x1_all, g_all, out_x1, out_ret1, out_ret1c, E, n);
}

// Round 8
// 1049.486 us; speedup vs baseline: 2.7422x; 2.7422x over previous
//
#include <hip/hip_runtime.h>
#include <hip/hip_bf16.h>

// Problem constants (fixed by reference)
#define NN 8192
#define NMASK 8191
#define IND 3000
#define H1 256
#define OUTD 64
#define GRID 768     // 3 blocks/CU on 256 CUs — co-resident (capacity ~8 blocks/CU at our VGPR/LDS)
#define BLOCK 256

typedef __bf16 bf16x8 __attribute__((ext_vector_type(8)));
typedef float floatx4 __attribute__((ext_vector_type(4)));

__device__ __forceinline__ unsigned short f2b(float f) {
    __hip_bfloat16 h = __float2bfloat16(f);
    unsigned short u;
    __builtin_memcpy(&u, &h, 2);
    return u;
}

// ---------------- shared-memory union (max 19216 B) ----------------

union SMem {
    struct { unsigned short As[64 * 72]; unsigned short Bs[64 * 72]; } gemm;  // 18432
    float ttile[64][65];                                                       // 16640
    struct { int colS[64]; int pcolS[64]; float wS[64]; } agg;                 // 768
    struct {                                                                   // 19216
        float WdS[64][65];                 // persists across rows
        float sa[4][64]; float sc[4][64]; float sr[4];
        float gS[64]; float gcS[64];
    } rb;
    int scan[256];
    int cnt[2];
};

// ---------------- grid barrier: monotonic count, RELAXED spin (no invalidate storm) ----
// bar[0] zeroed by the pre-kernel hipMemsetAsync. Arrival: RELEASE fetch_add
// (writes back this block's stores). Spin: RELAXED load — no cache maintenance.
// Exit: one ACQUIRE load — single invalidate to observe other blocks' stores.

__device__ __forceinline__ void gridbar(int* bar, int target) {
    __syncthreads();
    if (threadIdx.x == 0) {
        __hip_atomic_fetch_add(&bar[0], 1, __ATOMIC_RELEASE, __HIP_MEMORY_SCOPE_AGENT);
        while (__hip_atomic_load(&bar[0], __ATOMIC_RELAXED, __HIP_MEMORY_SCOPE_AGENT) < target)
            __builtin_amdgcn_s_sleep(2);
        (void)__hip_atomic_load(&bar[0], __ATOMIC_ACQUIRE, __HIP_MEMORY_SCOPE_AGENT);
    }
    __syncthreads();
}

// ---------------- GEMM tile: C[m0:m0+64, n0:n0+64] = A @ Bt^T ----------------
// A fp32 (AFP32=1) or bf16; Bt bf16 K-major; C fp32. BK=64, 4 waves.

template <int AFP32>
__device__ void gemm_tile(unsigned short* As, unsigned short* Bs,
                          const void* __restrict__ Araw, const __hip_bfloat16* __restrict__ Bt,
                          float* __restrict__ C, int m0, int n0, int N, int K) {
    int t = threadIdx.x;
    int lane = t & 63;
    int w = t >> 6;
    int srow = t >> 2;
    int kc = (t & 3) * 16;
    floatx4 acc0 = {0.f, 0.f, 0.f, 0.f}, acc1 = acc0, acc2 = acc0, acc3 = acc0;
    int msub = w * 16;
    int arow = msub + (lane & 15);
    int koff = (lane >> 4) * 8;
    int nlo = lane & 15;

    for (int k0 = 0; k0 < K; k0 += 64) {
        unsigned short a16[16] = {0};
        unsigned short b16[16] = {0};
#pragma unroll
        for (int h = 0; h < 2; ++h) {
            int kk = k0 + kc + h * 8;
            if (kk < K) {  // K % 8 == 0: in-bounds start => full chunk in bounds
                if (AFP32) {
                    const float* ap = (const float*)Araw + (size_t)(m0 + srow) * K + kk;
                    float4 f0 = *reinterpret_cast<const float4*>(ap);
                    float4 f1 = *reinterpret_cast<const float4*>(ap + 4);
                    a16[h * 8 + 0] = f2b(f0.x); a16[h * 8 + 1] = f2b(f0.y);
                    a16[h * 8 + 2] = f2b(f0.z); a16[h * 8 + 3] = f2b(f0.w);
                    a16[h * 8 + 4] = f2b(f1.x); a16[h * 8 + 5] = f2b(f1.y);
                    a16[h * 8 + 6] = f2b(f1.z); a16[h * 8 + 7] = f2b(f1.w);
                } else {
                    uint4 v = *reinterpret_cast<const uint4*>(
                        (const unsigned short*)Araw + (size_t)(m0 + srow) * K + kk);
                    __builtin_memcpy(&a16[h * 8], &v, 16);
                }
                uint4 bvv = *reinterpret_cast<const uint4*>(
                    (const unsigned short*)Bt + (size_t)(n0 + srow) * K + kk);
                __builtin_memcpy(&b16[h * 8], &bvv, 16);
            }
        }
        __syncthreads();
        *reinterpret_cast<uint4*>(&As[srow * 72 + kc]) = *reinterpret_cast<uint4*>(&a16[0]);
        *reinterpret_cast<uint4*>(&As[srow * 72 + kc + 8]) = *reinterpret_cast<uint4*>(&a16[8]);
        *reinterpret_cast<uint4*>(&Bs[srow * 72 + kc]) = *reinterpret_cast<uint4*>(&b16[0]);
        *reinterpret_cast<uint4*>(&Bs[srow * 72 + kc + 8]) = *reinterpret_cast<uint4*>(&b16[8]);
        __syncthreads();
        bf16x8 a0 = *reinterpret_cast<const bf16x8*>(&As[arow * 72 + koff]);
        bf16x8 a1 = *reinterpret_cast<const bf16x8*>(&As[arow * 72 + 32 + koff]);
#pragma unroll
        for (int j = 0; j < 4; ++j) {
            bf16x8 b0 = *reinterpret_cast<const bf16x8*>(&Bs[(j * 16 + nlo) * 72 + koff]);
            bf16x8 b1 = *reinterpret_cast<const bf16x8*>(&Bs[(j * 16 + nlo) * 72 + 32 + koff]);
            floatx4* ac = (j == 0) ? &acc0 : (j == 1) ? &acc1 : (j == 2) ? &acc2 : &acc3;
            *ac = __builtin_amdgcn_mfma_f32_16x16x32_bf16(a0, b0, *ac, 0, 0, 0);
            *ac = __builtin_amdgcn_mfma_f32_16x16x32_bf16(a1, b1, *ac, 0, 0, 0);
        }
    }
    // C/D layout: col = lane&15, row = (lane>>4)*4 + r  [verified m89/m91]
    int crow = msub + (lane >> 4) * 4;
    int ccol = lane & 15;
    floatx4 accs[4] = {acc0, acc1, acc2, acc3};
#pragma unroll
    for (int j = 0; j < 4; ++j) {
#pragma unroll
        for (int r = 0; r < 4; ++r) {
            C[(size_t)(m0 + crow + r) * N + (n0 + j * 16 + ccol)] = accs[j][r];
        }
    }
}

// ---------------- LDS-tiled fp32->bf16 transpose tile ----------------

__device__ void transpose_tile(SMem& sm, const float* __restrict__ in,
                               __hip_bfloat16* __restrict__ out, int R, int C,
                               int cx, int ry) {
    int c0 = cx * 64;
    int r0 = ry * 64;
    int t = threadIdx.x;
    int tc = t & 63;
    int tq = t >> 6;
    __syncthreads();
#pragma unroll
    for (int s = 0; s < 16; ++s) {
        int rr = tq + s * 4;
        int r = r0 + rr;
        sm.ttile[rr][tc] = (r < R) ? in[(size_t)r * C + c0 + tc] : 0.f;
    }
    __syncthreads();
#pragma unroll
    for (int s = 0; s < 16; ++s) {
        int cc = tq + s * 4;
        int r = r0 + tc;
        if (r < R) out[(size_t)(c0 + cc) * R + r] = __float2bfloat16(sm.ttile[tc][cc]);
    }
}

// ---------------- the megakernel ----------------

__global__ __launch_bounds__(256, 4) void k_mega(
    const float* __restrict__ gene, const float* __restrict__ mask,
    const float* __restrict__ W1, const float* __restrict__ b1,
    const float* __restrict__ W2, const float* __restrict__ b2,
    const float* __restrict__ Wd, const float* __restrict__ bd,
    const unsigned* __restrict__ eidx_raw, const unsigned* __restrict__ perm_raw,
    int* bar, int* deg, int* eidx32, int* perm32, int* row_ptr, int* cursor,
    float* dinv, int* col, __hip_bfloat16* W1t, __hip_bfloat16* W2t,
    float* xw1, __hip_bfloat16* h_all, float* hw_all, float* x1_all,
    float* out_x1, float* out_ret1, float* out_ret1c, int E, int n) {
    __shared__ __align__(16) SMem sm;
    const int tid = threadIdx.x;
    const int bid = blockIdx.x;
    int bt = 0;

    // ---- S0a: index-width detection (per-block, 256 sampled pairs) ----
    if (tid < 2) sm.cnt[tid] = 0;
    __syncthreads();
    {
        if (eidx_raw[2 * tid + 1] == 0u) atomicAdd(&sm.cnt[0], 1);
        if (perm_raw[2 * tid + 1] == 0u) atomicAdd(&sm.cnt[1], 1);
    }
    __syncthreads();
    const int f_e = sm.cnt[0] > 128;
    const int f_p = sm.cnt[1] > 128;

    // ---- S0b: normalize indices + fused degree count ----
    for (int i = bid * BLOCK + tid; i < 2 * E; i += GRID * BLOCK) {
        unsigned v = f_e ? eidx_raw[2 * (size_t)i] : eidx_raw[i];
        int x = (int)(v & (unsigned)NMASK);
        eidx32[i] = x;
        if (i >= E) atomicAdd(&deg[x], 1);
    }
    for (int i = bid * BLOCK + tid; i < n; i += GRID * BLOCK) {
        unsigned v = f_p ? perm_raw[2 * (size_t)i] : perm_raw[i];
        perm32[i] = (int)(v & (unsigned)NMASK);
    }
    gridbar(bar, bt += GRID);

    // ---- S1: block 0 scans degrees; blocks 1..192 transpose weights ----
    if (bid == 0) {
        int per = n / BLOCK;  // 32
        int base = tid * per;
        int s = 0;
        for (int u = 0; u < per; ++u) s += deg[base + u];
        sm.scan[tid] = s;
        __syncthreads();
        for (int off = 1; off < BLOCK; off <<= 1) {
            int v = (tid >= off) ? sm.scan[tid - off] : 0;
            __syncthreads();
            sm.scan[tid] += v;
            __syncthreads();
        }
        int run = tid ? sm.scan[tid - 1] : 0;
        for (int u = 0; u < per; ++u) {
            int i = base + u;
            int d = deg[i];
            row_ptr[i] = run;
            cursor[i] = run;
            dinv[i] = rsqrtf((float)(1 + d));
            run += d;
        }
        if (tid == BLOCK - 1) row_ptr[n] = run;
    } else if (bid <= 188) {
        int tile = bid - 1;                                       // 188 tiles: 4 x 47
        transpose_tile(sm, W1, W1t, IND, H1, tile & 3, tile >> 2);
    } else if (bid <= 192) {
        transpose_tile(sm, W2, W2t, H1, OUTD, 0, bid - 189);      // 4 tiles
    }
    gridbar(bar, bt += GRID);

    // ---- S2: GEMM1 (blocks 0..511) overlapped with CSR scatter (blocks 512..767) ----
    if (bid < 512) {
        gemm_tile<1>(sm.gemm.As, sm.gemm.Bs, gene, W1t, xw1,
                     (bid & 127) * 64, (bid >> 7) * 64, H1, IND);
    } else {
        for (int e = (bid - 512) * BLOCK + tid; e < E; e += 256 * BLOCK) {
            int d = eidx32[E + e];
            int pos = atomicAdd(&cursor[d], 1);
            if (pos >= 0 && pos < E) col[pos] = eidx32[e];
        }
    }
    gridbar(bar, bt += GRID);

    // ---- S3: conv1 aggregation (both graphs) -> h_all bf16 [2n x 256] ----
    for (int i = bid; i < n; i += GRID) {
        int c = tid;
        float di = dinv[i];
        int pi = perm32[i];
        float sw = di * di;
        float acc = sw * xw1[(size_t)i * H1 + c];
        float accc = sw * xw1[(size_t)pi * H1 + c];
        int s = row_ptr[i], e = row_ptr[i + 1];
        for (int base = s; base < e; base += 64) {
            int cnt2 = min(64, e - base);
            __syncthreads();
            if (c < cnt2) {
                int j = col[base + c];
                sm.agg.colS[c] = j;
                sm.agg.wS[c] = di * dinv[j];
                sm.agg.pcolS[c] = perm32[j];
            }
            __syncthreads();
#pragma unroll 4
            for (int u = 0; u < cnt2; ++u) {
                float wv = sm.agg.wS[u];
                acc += wv * xw1[(size_t)sm.agg.colS[u] * H1 + c];
                accc += wv * xw1[(size_t)sm.agg.pcolS[u] * H1 + c];
            }
        }
        float b = b1[c];
        h_all[(size_t)i * H1 + c] = __float2bfloat16(fmaxf(acc + b, 0.f));
        h_all[(size_t)(n + i) * H1 + c] = __float2bfloat16(fmaxf(accc + b, 0.f));
        __syncthreads();
    }
    gridbar(bar, bt += GRID);

    // ---- S4: GEMM2 hw_all = h_all(bf16) @ W2t  (256 tiles) ----
    if (bid < 256) {
        gemm_tile<0>(sm.gemm.As, sm.gemm.Bs, h_all, W2t, hw_all, bid * 64, 0, OUTD, H1);
    }
    gridbar(bar, bt += GRID);

    // ---- S5: conv2 aggregation -> x1_all fp32 [2n x 64]; x1 to d_out ----
    {
        int lane = tid & 63;
        for (int i = bid * 4 + (tid >> 6); i < n; i += GRID * 4) {
            float di = dinv[i];
            float sw = di * di;
            float acc = sw * hw_all[(size_t)i * OUTD + lane];
            float accc = sw * hw_all[(size_t)(n + i) * OUTD + lane];
            int s = row_ptr[i], e = row_ptr[i + 1];
            for (int k = s; k < e; ++k) {
                int j = col[k];
                float wv = di * dinv[j];
                acc += wv * hw_all[(size_t)j * OUTD + lane];
                accc += wv * hw_all[(size_t)(n + j) * OUTD + lane];
            }
            float b = b2[lane];
            float v = fmaxf(acc + b, 0.f);
            float vc = fmaxf(accc + b, 0.f);
            x1_all[(size_t)i * OUTD + lane] = v;
            x1_all[(size_t)(n + i) * OUTD + lane] = vc;
            out_x1[(size_t)i * OUTD + lane] = v;
        }
    }
    gridbar(bar, bt += GRID);

    // ---- S6: readout + L2-normalize + sigmoid + FUSED bilinear per row ----
    {
        __syncthreads();
        for (int u = tid; u < 64 * 64; u += BLOCK) sm.rb.WdS[u >> 6][u & 63] = Wd[u];
        __syncthreads();
        int lane = tid & 63;
        int w = tid >> 6;
        float bdv = bd[0];
        for (int i = bid; i < n; i += GRID) {
            float acc = 0.f, accc = 0.f, rs = 0.f;
            const float* mrow = mask + (size_t)i * n;
            int qbase = w * (n >> 2);
            float4 q[8];
#pragma unroll
            for (int it = 0; it < 8; ++it)
                q[it] = *reinterpret_cast<const float4*>(mrow + qbase + it * 256 + lane * 4);
#pragma unroll
            for (int it = 0; it < 8; ++it) {
                bool nz = (q[it].x != 0.f) || (q[it].y != 0.f) || (q[it].z != 0.f) || (q[it].w != 0.f);
                unsigned long long bal = __ballot(nz);
                while (bal) {
                    int l = __builtin_ctzll(bal);
                    bal &= bal - 1;
                    float s0 = __shfl(q[it].x, l), s1 = __shfl(q[it].y, l);
                    float s2 = __shfl(q[it].z, l), s3 = __shfl(q[it].w, l);
                    int j0 = qbase + it * 256 + l * 4;
                    float sv[4] = {s0, s1, s2, s3};
#pragma unroll
                    for (int u = 0; u < 4; ++u) {
                        if (sv[u] != 0.f) {
                            float m = sv[u];
                            int j = j0 + u;
                            acc += m * x1_all[(size_t)j * OUTD + lane];
                            accc += m * x1_all[(size_t)(n + j) * OUTD + lane];
                            rs += m;
                        }
                    }
                }
            }
            __syncthreads();
            sm.rb.sa[w][lane] = acc;
            sm.rb.sc[w][lane] = accc;
            if (lane == 0) sm.rb.sr[w] = rs;
            __syncthreads();
            if (w == 0) {
                float tot = sm.rb.sa[0][lane] + sm.rb.sa[1][lane] + sm.rb.sa[2][lane] + sm.rb.sa[3][lane];
                float totc = sm.rb.sc[0][lane] + sm.rb.sc[1][lane] + sm.rb.sc[2][lane] + sm.rb.sc[3][lane];
                float rst = fmaxf(sm.rb.sr[0] + sm.rb.sr[1] + sm.rb.sr[2] + sm.rb.sr[3], 1e-20f);
                float g = tot / rst;
                float gc = totc / rst;
                float s1 = g * g, s2 = gc * gc;
#pragma unroll
                for (int off = 32; off; off >>= 1) {
                    s1 += __shfl_xor(s1, off);
                    s2 += __shfl_xor(s2, off);
                }
                float gsig = 1.f / (1.f + __expf(-(g / fmaxf(sqrtf(s1), 1e-12f))));
                float gcsig = 1.f / (1.f + __expf(-(gc / fmaxf(sqrtf(s2), 1e-12f))));
                sm.rb.gS[lane] = gsig;
                sm.rb.gcS[lane] = gcsig;
                float tg = 0.f, tgc = 0.f;
#pragma unroll 8
                for (int j = 0; j < 64; ++j) {
                    float wv = sm.rb.WdS[lane][j];
                    tg += wv * sm.rb.gS[j];
                    tgc += wv * sm.rb.gcS[j];
                }
                float x = x1_all[(size_t)i * OUTD + lane];
                float xc = x1_all[(size_t)(n + i) * OUTD + lane];
                float r0 = x * tg, r1 = xc * tg, r2 = xc * tgc, r3 = x * tgc;
#pragma unroll
                for (int off = 32; off; off >>= 1) {
                    r0 += __shfl_down(r0, off);
                    r1 += __shfl_down(r1, off);
                    r2 += __shfl_down(r2, off);
                    r3 += __shfl_down(r3, off);
                }
                if (lane == 0) {
                    out_ret1[(size_t)i * 2 + 0] = r0 + bdv;
                    out_ret1[(size_t)i * 2 + 1] = r1 + bdv;
                    out_ret1c[(size_t)i * 2 + 0] = r2 + bdv;
                    out_ret1c[(size_t)i * 2 + 1] = r3 + bdv;
                }
            }
            __syncthreads();
        }
    }
}

// ---------------- ws-size probe ----------------

__global__ void k_probe(float code, float* out) {
    if (threadIdx.x == 0 && blockIdx.x == 0) out[0] = code;
}

// ---------------- host ----------------

extern "C" void kernel_launch(void* const* d_in, const int* in_sizes, int n_in,
                              void* d_out, int out_size, void* d_ws, size_t ws_size,
                              hipStream_t stream) {
    const float* gene = (const float*)d_in[0];
    const float* mask = (const float*)d_in[1];
    const float* W1 = (const float*)d_in[2];
    const float* b1 = (const float*)d_in[3];
    const float* W2 = (const float*)d_in[4];
    const float* b2 = (const float*)d_in[5];
    const float* Wd = (const float*)d_in[6];
    const float* bd = (const float*)d_in[7];
    const unsigned* eidx_raw = (const unsigned*)d_in[8];
    const unsigned* perm_raw = (const unsigned*)d_in[9];
    const int n = NN;
    const int E = in_sizes[8] / 2;  // 131072 logical edges

    // workspace carve-up (256B aligned); bar+deg adjacent for one memset
    char* base = (char*)d_ws;
    char* p = base;
    auto alloc = [&](size_t bytes) -> char* {
        char* r = p;
        p += (bytes + 255) & ~(size_t)255;
        return r;
    };
    int* bar = (int*)alloc(256);
    int* deg = (int*)alloc((size_t)n * 4);
    int* eidx32 = (int*)alloc((size_t)2 * E * 4);
    int* perm32 = (int*)alloc((size_t)n * 4);
    int* row_ptr = (int*)alloc((size_t)(n + 1) * 4);
    int* cursor = (int*)alloc((size_t)n * 4);
    float* dinv = (float*)alloc((size_t)n * 4);
    int* col = (int*)alloc((size_t)E * 4);
    __hip_bfloat16* W2t = (__hip_bfloat16*)alloc((size_t)H1 * OUTD * 2);
    __hip_bfloat16* W1t = (__hip_bfloat16*)alloc((size_t)IND * H1 * 2);
    float* xw1 = (float*)alloc((size_t)n * H1 * 4);                         // 8 MB
    __hip_bfloat16* h_all = (__hip_bfloat16*)alloc((size_t)2 * n * H1 * 2); // 8 MB
    size_t need = (size_t)(p - base);
    // aliases into dead buffers:
    float* hw_all = xw1;                         // xw1 dead after agg1
    float* x1_all = xw1 + (size_t)2 * n * OUTD;  // second half of xw1's 8 MB

    float* out_x1 = (float*)d_out;
    float* out_ret1 = out_x1 + (size_t)n * OUTD;
    float* out_ret1c = out_ret1 + (size_t)n * 2;

    if (ws_size < need) {
        k_probe<<<1, 64, 0, stream>>>(1000.f + (float)(ws_size >> 20), out_x1);
        return;
    }

    // zero barrier + degree counters (stream-ordered, graph-capturable)
    hipMemsetAsync(bar, 0, 256 + (size_t)n * 4, stream);

    k_mega<<<GRID, BLOCK, 0, stream>>>(
        gene, mask, W1, b1, W2, b2, Wd, bd, eidx_raw, perm_raw,
        bar, deg, eidx32, perm32, row_ptr, cursor, dinv, col, W1t, W2t,
        xw1, h_all, hw_all, x1_all, out_x1, out_ret1, out_ret1c, E, n);
}

// Round 9
// 777.015 us; speedup vs baseline: 3.7037x; 1.3507x over previous
//
#include <hip/hip_runtime.h>
#include <hip/hip_bf16.h>

// Problem constants (fixed by reference)
#define NN 8192
#define NMASK 8191
#define IND 3000
#define H1 256
#define OUTD 64
#define GRID 768     // 3 blocks/CU on 256 CUs — co-resident (proven R7/R8)
#define BLOCK 256
#define NLINES 16    // arrival sub-counters; GRID/NLINES = 48 arrivals per line

typedef __bf16 bf16x8 __attribute__((ext_vector_type(8)));
typedef float floatx4 __attribute__((ext_vector_type(4)));

__device__ __forceinline__ unsigned short f2b(float f) {
    __hip_bfloat16 h = __float2bfloat16(f);
    unsigned short u;
    __builtin_memcpy(&u, &h, 2);
    return u;
}

// ---------------- shared-memory union (max 19216 B) ----------------

union SMem {
    struct { unsigned short As[64 * 72]; unsigned short Bs[64 * 72]; } gemm;  // 18432
    float ttile[64][65];                                                       // 16640
    struct { int colS[64]; int pcolS[64]; float wS[64]; } agg;                 // 768
    struct {                                                                   // 19216
        float WdS[64][65];
        float sa[4][64]; float sc[4][64]; float sr[4];
        float gS[64]; float gcS[64];
    } rb;
    int scan[256];
    int cnt[2];
};

// ---------------- contention-proof grid barrier ----------------
// Layout (ints, 1 KB line spacing): bar[1024*k] k=0..15 sub-counters;
// bar[1024*16] master; bar[1024*17] generation flag. All zeroed pre-kernel.
// Arrivals: ACQ_REL fetch_add on sub-line (48/line/gen); sub-last ACQ_REL
// fetch_add master (16/gen); master-last RELEASE-stores gen flag.
// Spin: RELAXED + s_sleep(64) (~1.7us period; no poll flood); ACQUIRE on exit.

__device__ __forceinline__ void gridbar(int* bar, int g) {
    __syncthreads();
    if (threadIdx.x == 0) {
        int* sub = &bar[1024 * (blockIdx.x & (NLINES - 1))];
        int old = __hip_atomic_fetch_add(sub, 1, __ATOMIC_ACQ_REL, __HIP_MEMORY_SCOPE_AGENT);
        if (old == (GRID / NLINES) * g - 1) {
            int mo = __hip_atomic_fetch_add(&bar[1024 * 16], 1, __ATOMIC_ACQ_REL,
                                            __HIP_MEMORY_SCOPE_AGENT);
            if (mo == NLINES * g - 1)
                __hip_atomic_store(&bar[1024 * 17], g, __ATOMIC_RELEASE,
                                   __HIP_MEMORY_SCOPE_AGENT);
        }
        while (__hip_atomic_load(&bar[1024 * 17], __ATOMIC_RELAXED,
                                 __HIP_MEMORY_SCOPE_AGENT) < g)
            __builtin_amdgcn_s_sleep(64);
        (void)__hip_atomic_load(&bar[1024 * 17], __ATOMIC_ACQUIRE, __HIP_MEMORY_SCOPE_AGENT);
    }
    __syncthreads();
}

// ---------------- GEMM tile: C[m0:m0+64, n0:n0+64] = A @ Bt^T ----------------
// A fp32 (AFP32=1) or bf16; Bt bf16 K-major; C fp32. BK=64, 4 waves.

template <int AFP32>
__device__ void gemm_tile(unsigned short* As, unsigned short* Bs,
                          const void* __restrict__ Araw, const __hip_bfloat16* __restrict__ Bt,
                          float* __restrict__ C, int m0, int n0, int N, int K) {
    int t = threadIdx.x;
    int lane = t & 63;
    int w = t >> 6;
    int srow = t >> 2;
    int kc = (t & 3) * 16;
    floatx4 acc0 = {0.f, 0.f, 0.f, 0.f}, acc1 = acc0, acc2 = acc0, acc3 = acc0;
    int msub = w * 16;
    int arow = msub + (lane & 15);
    int koff = (lane >> 4) * 8;
    int nlo = lane & 15;

    for (int k0 = 0; k0 < K; k0 += 64) {
        unsigned short a16[16] = {0};
        unsigned short b16[16] = {0};
#pragma unroll
        for (int h = 0; h < 2; ++h) {
            int kk = k0 + kc + h * 8;
            if (kk < K) {  // K % 8 == 0: in-bounds start => full chunk in bounds
                if (AFP32) {
                    const float* ap = (const float*)Araw + (size_t)(m0 + srow) * K + kk;
                    float4 f0 = *reinterpret_cast<const float4*>(ap);
                    float4 f1 = *reinterpret_cast<const float4*>(ap + 4);
                    a16[h * 8 + 0] = f2b(f0.x); a16[h * 8 + 1] = f2b(f0.y);
                    a16[h * 8 + 2] = f2b(f0.z); a16[h * 8 + 3] = f2b(f0.w);
                    a16[h * 8 + 4] = f2b(f1.x); a16[h * 8 + 5] = f2b(f1.y);
                    a16[h * 8 + 6] = f2b(f1.z); a16[h * 8 + 7] = f2b(f1.w);
                } else {
                    uint4 v = *reinterpret_cast<const uint4*>(
                        (const unsigned short*)Araw + (size_t)(m0 + srow) * K + kk);
                    __builtin_memcpy(&a16[h * 8], &v, 16);
                }
                uint4 bvv = *reinterpret_cast<const uint4*>(
                    (const unsigned short*)Bt + (size_t)(n0 + srow) * K + kk);
                __builtin_memcpy(&b16[h * 8], &bvv, 16);
            }
        }
        __syncthreads();
        *reinterpret_cast<uint4*>(&As[srow * 72 + kc]) = *reinterpret_cast<uint4*>(&a16[0]);
        *reinterpret_cast<uint4*>(&As[srow * 72 + kc + 8]) = *reinterpret_cast<uint4*>(&a16[8]);
        *reinterpret_cast<uint4*>(&Bs[srow * 72 + kc]) = *reinterpret_cast<uint4*>(&b16[0]);
        *reinterpret_cast<uint4*>(&Bs[srow * 72 + kc + 8]) = *reinterpret_cast<uint4*>(&b16[8]);
        __syncthreads();
        bf16x8 a0 = *reinterpret_cast<const bf16x8*>(&As[arow * 72 + koff]);
        bf16x8 a1 = *reinterpret_cast<const bf16x8*>(&As[arow * 72 + 32 + koff]);
#pragma unroll
        for (int j = 0; j < 4; ++j) {
            bf16x8 b0 = *reinterpret_cast<const bf16x8*>(&Bs[(j * 16 + nlo) * 72 + koff]);
            bf16x8 b1 = *reinterpret_cast<const bf16x8*>(&Bs[(j * 16 + nlo) * 72 + 32 + koff]);
            floatx4* ac = (j == 0) ? &acc0 : (j == 1) ? &acc1 : (j == 2) ? &acc2 : &acc3;
            *ac = __builtin_amdgcn_mfma_f32_16x16x32_bf16(a0, b0, *ac, 0, 0, 0);
            *ac = __builtin_amdgcn_mfma_f32_16x16x32_bf16(a1, b1, *ac, 0, 0, 0);
        }
    }
    // C/D layout: col = lane&15, row = (lane>>4)*4 + r  [verified m89/m91]
    int crow = msub + (lane >> 4) * 4;
    int ccol = lane & 15;
    floatx4 accs[4] = {acc0, acc1, acc2, acc3};
#pragma unroll
    for (int j = 0; j < 4; ++j) {
#pragma unroll
        for (int r = 0; r < 4; ++r) {
            C[(size_t)(m0 + crow + r) * N + (n0 + j * 16 + ccol)] = accs[j][r];
        }
    }
}

// ---------------- LDS-tiled fp32->bf16 transpose tile ----------------

__device__ void transpose_tile(SMem& sm, const float* __restrict__ in,
                               __hip_bfloat16* __restrict__ out, int R, int C,
                               int cx, int ry) {
    int c0 = cx * 64;
    int r0 = ry * 64;
    int t = threadIdx.x;
    int tc = t & 63;
    int tq = t >> 6;
    __syncthreads();
#pragma unroll
    for (int s = 0; s < 16; ++s) {
        int rr = tq + s * 4;
        int r = r0 + rr;
        sm.ttile[rr][tc] = (r < R) ? in[(size_t)r * C + c0 + tc] : 0.f;
    }
    __syncthreads();
#pragma unroll
    for (int s = 0; s < 16; ++s) {
        int cc = tq + s * 4;
        int r = r0 + tc;
        if (r < R) out[(size_t)(c0 + cc) * R + r] = __float2bfloat16(sm.ttile[tc][cc]);
    }
}

// ---------------- the megakernel ----------------

__global__ __launch_bounds__(256, 4) void k_mega(
    const float* __restrict__ gene, const float* __restrict__ mask,
    const float* __restrict__ W1, const float* __restrict__ b1,
    const float* __restrict__ W2, const float* __restrict__ b2,
    const float* __restrict__ Wd, const float* __restrict__ bd,
    const unsigned* __restrict__ eidx_raw, const unsigned* __restrict__ perm_raw,
    int* bar, int* deg, int* eidx32, int* perm32, int* row_ptr, int* cursor,
    float* dinv, int* col, __hip_bfloat16* W1t, __hip_bfloat16* W2t,
    float* xw1, __hip_bfloat16* h_all, float* hw_all, float* x1_all,
    float* out_x1, float* out_ret1, float* out_ret1c, int E, int n) {
    __shared__ __align__(16) SMem sm;
    const int tid = threadIdx.x;
    const int bid = blockIdx.x;
    int gen = 0;

    // ---- S0a: index-width detection (per-block, 256 sampled pairs) ----
    if (tid < 2) sm.cnt[tid] = 0;
    __syncthreads();
    {
        if (eidx_raw[2 * tid + 1] == 0u) atomicAdd(&sm.cnt[0], 1);
        if (perm_raw[2 * tid + 1] == 0u) atomicAdd(&sm.cnt[1], 1);
    }
    __syncthreads();
    const int f_e = sm.cnt[0] > 128;
    const int f_p = sm.cnt[1] > 128;

    // ---- S0b: normalize indices + fused degree count ----
    for (int i = bid * BLOCK + tid; i < 2 * E; i += GRID * BLOCK) {
        unsigned v = f_e ? eidx_raw[2 * (size_t)i] : eidx_raw[i];
        int x = (int)(v & (unsigned)NMASK);
        eidx32[i] = x;
        if (i >= E) atomicAdd(&deg[x], 1);
    }
    for (int i = bid * BLOCK + tid; i < n; i += GRID * BLOCK) {
        unsigned v = f_p ? perm_raw[2 * (size_t)i] : perm_raw[i];
        perm32[i] = (int)(v & (unsigned)NMASK);
    }
    gridbar(bar, ++gen);

    // ---- S1: block 0 scans degrees; blocks 1..192 transpose weights ----
    if (bid == 0) {
        int per = n / BLOCK;  // 32
        int base = tid * per;
        int s = 0;
        for (int u = 0; u < per; ++u) s += deg[base + u];
        sm.scan[tid] = s;
        __syncthreads();
        for (int off = 1; off < BLOCK; off <<= 1) {
            int v = (tid >= off) ? sm.scan[tid - off] : 0;
            __syncthreads();
            sm.scan[tid] += v;
            __syncthreads();
        }
        int run = tid ? sm.scan[tid - 1] : 0;
        for (int u = 0; u < per; ++u) {
            int i = base + u;
            int d = deg[i];
            row_ptr[i] = run;
            cursor[i] = run;
            dinv[i] = rsqrtf((float)(1 + d));
            run += d;
        }
        if (tid == BLOCK - 1) row_ptr[n] = run;
    } else if (bid <= 188) {
        int tile = bid - 1;                                       // 188 tiles: 4 x 47
        transpose_tile(sm, W1, W1t, IND, H1, tile & 3, tile >> 2);
    } else if (bid <= 192) {
        transpose_tile(sm, W2, W2t, H1, OUTD, 0, bid - 189);      // 4 tiles
    }
    gridbar(bar, ++gen);

    // ---- S2: GEMM1 (blocks 0..511) overlapped with CSR scatter (blocks 512..767) ----
    if (bid < 512) {
        gemm_tile<1>(sm.gemm.As, sm.gemm.Bs, gene, W1t, xw1,
                     (bid & 127) * 64, (bid >> 7) * 64, H1, IND);
    } else {
        for (int e = (bid - 512) * BLOCK + tid; e < E; e += 256 * BLOCK) {
            int d = eidx32[E + e];
            int pos = atomicAdd(&cursor[d], 1);
            if (pos >= 0 && pos < E) col[pos] = eidx32[e];
        }
    }
    gridbar(bar, ++gen);

    // ---- S3: conv1 aggregation (both graphs) -> h_all bf16 [2n x 256] ----
    for (int i = bid; i < n; i += GRID) {
        int c = tid;
        float di = dinv[i];
        int pi = perm32[i];
        float sw = di * di;
        float acc = sw * xw1[(size_t)i * H1 + c];
        float accc = sw * xw1[(size_t)pi * H1 + c];
        int s = row_ptr[i], e = row_ptr[i + 1];
        for (int base = s; base < e; base += 64) {
            int cnt2 = min(64, e - base);
            __syncthreads();
            if (c < cnt2) {
                int j = col[base + c];
                sm.agg.colS[c] = j;
                sm.agg.wS[c] = di * dinv[j];
                sm.agg.pcolS[c] = perm32[j];
            }
            __syncthreads();
#pragma unroll 4
            for (int u = 0; u < cnt2; ++u) {
                float wv = sm.agg.wS[u];
                acc += wv * xw1[(size_t)sm.agg.colS[u] * H1 + c];
                accc += wv * xw1[(size_t)sm.agg.pcolS[u] * H1 + c];
            }
        }
        float b = b1[c];
        h_all[(size_t)i * H1 + c] = __float2bfloat16(fmaxf(acc + b, 0.f));
        h_all[(size_t)(n + i) * H1 + c] = __float2bfloat16(fmaxf(accc + b, 0.f));
        __syncthreads();
    }
    gridbar(bar, ++gen);

    // ---- S4: GEMM2 hw_all = h_all(bf16) @ W2t  (256 tiles) ----
    if (bid < 256) {
        gemm_tile<0>(sm.gemm.As, sm.gemm.Bs, h_all, W2t, hw_all, bid * 64, 0, OUTD, H1);
    }
    gridbar(bar, ++gen);

    // ---- S5: conv2 aggregation -> x1_all fp32 [2n x 64]; x1 to d_out ----
    {
        int lane = tid & 63;
        for (int i = bid * 4 + (tid >> 6); i < n; i += GRID * 4) {
            float di = dinv[i];
            float sw = di * di;
            float acc = sw * hw_all[(size_t)i * OUTD + lane];
            float accc = sw * hw_all[(size_t)(n + i) * OUTD + lane];
            int s = row_ptr[i], e = row_ptr[i + 1];
            for (int k = s; k < e; ++k) {
                int j = col[k];
                float wv = di * dinv[j];
                acc += wv * hw_all[(size_t)j * OUTD + lane];
                accc += wv * hw_all[(size_t)(n + j) * OUTD + lane];
            }
            float b = b2[lane];
            float v = fmaxf(acc + b, 0.f);
            float vc = fmaxf(accc + b, 0.f);
            x1_all[(size_t)i * OUTD + lane] = v;
            x1_all[(size_t)(n + i) * OUTD + lane] = vc;
            out_x1[(size_t)i * OUTD + lane] = v;
        }
    }
    gridbar(bar, ++gen);

    // ---- S6: readout + L2-normalize + sigmoid + FUSED bilinear per row ----
    {
        __syncthreads();
        for (int u = tid; u < 64 * 64; u += BLOCK) sm.rb.WdS[u >> 6][u & 63] = Wd[u];
        __syncthreads();
        int lane = tid & 63;
        int w = tid >> 6;
        float bdv = bd[0];
        for (int i = bid; i < n; i += GRID) {
            float acc = 0.f, accc = 0.f, rs = 0.f;
            const float* mrow = mask + (size_t)i * n;
            int qbase = w * (n >> 2);
            float4 q[8];
#pragma unroll
            for (int it = 0; it < 8; ++it)
                q[it] = *reinterpret_cast<const float4*>(mrow + qbase + it * 256 + lane * 4);
#pragma unroll
            for (int it = 0; it < 8; ++it) {
                bool nz = (q[it].x != 0.f) || (q[it].y != 0.f) || (q[it].z != 0.f) || (q[it].w != 0.f);
                unsigned long long bal = __ballot(nz);
                while (bal) {
                    int l = __builtin_ctzll(bal);
                    bal &= bal - 1;
                    float s0 = __shfl(q[it].x, l), s1 = __shfl(q[it].y, l);
                    float s2 = __shfl(q[it].z, l), s3 = __shfl(q[it].w, l);
                    int j0 = qbase + it * 256 + l * 4;
                    float sv[4] = {s0, s1, s2, s3};
#pragma unroll
                    for (int u = 0; u < 4; ++u) {
                        if (sv[u] != 0.f) {
                            float m = sv[u];
                            int j = j0 + u;
                            acc += m * x1_all[(size_t)j * OUTD + lane];
                            accc += m * x1_all[(size_t)(n + j) * OUTD + lane];
                            rs += m;
                        }
                    }
                }
            }
            __syncthreads();
            sm.rb.sa[w][lane] = acc;
            sm.rb.sc[w][lane] = accc;
            if (lane == 0) sm.rb.sr[w] = rs;
            __syncthreads();
            if (w == 0) {
                float tot = sm.rb.sa[0][lane] + sm.rb.sa[1][lane] + sm.rb.sa[2][lane] + sm.rb.sa[3][lane];
                float totc = sm.rb.sc[0][lane] + sm.rb.sc[1][lane] + sm.rb.sc[2][lane] + sm.rb.sc[3][lane];
                float rst = fmaxf(sm.rb.sr[0] + sm.rb.sr[1] + sm.rb.sr[2] + sm.rb.sr[3], 1e-20f);
                float g = tot / rst;
                float gc = totc / rst;
                float s1 = g * g, s2 = gc * gc;
#pragma unroll
                for (int off = 32; off; off >>= 1) {
                    s1 += __shfl_xor(s1, off);
                    s2 += __shfl_xor(s2, off);
                }
                float gsig = 1.f / (1.f + __expf(-(g / fmaxf(sqrtf(s1), 1e-12f))));
                float gcsig = 1.f / (1.f + __expf(-(gc / fmaxf(sqrtf(s2), 1e-12f))));
                sm.rb.gS[lane] = gsig;
                sm.rb.gcS[lane] = gcsig;
                float tg = 0.f, tgc = 0.f;
#pragma unroll 8
                for (int j = 0; j < 64; ++j) {
                    float wv = sm.rb.WdS[lane][j];
                    tg += wv * sm.rb.gS[j];
                    tgc += wv * sm.rb.gcS[j];
                }
                float x = x1_all[(size_t)i * OUTD + lane];
                float xc = x1_all[(size_t)(n + i) * OUTD + lane];
                float r0 = x * tg, r1 = xc * tg, r2 = xc * tgc, r3 = x * tgc;
#pragma unroll
                for (int off = 32; off; off >>= 1) {
                    r0 += __shfl_down(r0, off);
                    r1 += __shfl_down(r1, off);
                    r2 += __shfl_down(r2, off);
                    r3 += __shfl_down(r3, off);
                }
                if (lane == 0) {
                    out_ret1[(size_t)i * 2 + 0] = r0 + bdv;
                    out_ret1[(size_t)i * 2 + 1] = r1 + bdv;
                    out_ret1c[(size_t)i * 2 + 0] = r2 + bdv;
                    out_ret1c[(size_t)i * 2 + 1] = r3 + bdv;
                }
            }
            __syncthreads();
        }
    }
}

// ---------------- ws-size probe ----------------

__global__ void k_probe(float code, float* out) {
    if (threadIdx.x == 0 && blockIdx.x == 0) out[0] = code;
}

// ---------------- host ----------------

extern "C" void kernel_launch(void* const* d_in, const int* in_sizes, int n_in,
                              void* d_out, int out_size, void* d_ws, size_t ws_size,
                              hipStream_t stream) {
    const float* gene = (const float*)d_in[0];
    const float* mask = (const float*)d_in[1];
    const float* W1 = (const float*)d_in[2];
    const float* b1 = (const float*)d_in[3];
    const float* W2 = (const float*)d_in[4];
    const float* b2 = (const float*)d_in[5];
    const float* Wd = (const float*)d_in[6];
    const float* bd = (const float*)d_in[7];
    const unsigned* eidx_raw = (const unsigned*)d_in[8];
    const unsigned* perm_raw = (const unsigned*)d_in[9];
    const int n = NN;
    const int E = in_sizes[8] / 2;  // 131072 logical edges

    // workspace carve-up (256B aligned); bar+deg adjacent for one memset
    char* base = (char*)d_ws;
    char* p = base;
    auto alloc = [&](size_t bytes) -> char* {
        char* r = p;
        p += (bytes + 255) & ~(size_t)255;
        return r;
    };
    int* bar = (int*)alloc(1024 * 18 * 4);  // 72 KB: 16 sub + master + gen, 1KB-int spacing
    int* deg = (int*)alloc((size_t)n * 4);
    int* eidx32 = (int*)alloc((size_t)2 * E * 4);
    int* perm32 = (int*)alloc((size_t)n * 4);
    int* row_ptr = (int*)alloc((size_t)(n + 1) * 4);
    int* cursor = (int*)alloc((size_t)n * 4);
    float* dinv = (float*)alloc((size_t)n * 4);
    int* col = (int*)alloc((size_t)E * 4);
    __hip_bfloat16* W2t = (__hip_bfloat16*)alloc((size_t)H1 * OUTD * 2);
    __hip_bfloat16* W1t = (__hip_bfloat16*)alloc((size_t)IND * H1 * 2);
    float* xw1 = (float*)alloc((size_t)n * H1 * 4);                         // 8 MB
    __hip_bfloat16* h_all = (__hip_bfloat16*)alloc((size_t)2 * n * H1 * 2); // 8 MB
    size_t need = (size_t)(p - base);
    // aliases into dead buffers:
    float* hw_all = xw1;                         // xw1 dead after agg1
    float* x1_all = xw1 + (size_t)2 * n * OUTD;  // second half of xw1's 8 MB

    float* out_x1 = (float*)d_out;
    float* out_ret1 = out_x1 + (size_t)n * OUTD;
    float* out_ret1c = out_ret1 + (size_t)n * 2;

    if (ws_size < need) {
        k_probe<<<1, 64, 0, stream>>>(1000.f + (float)(ws_size >> 20), out_x1);
        return;
    }

    // zero barrier lines + degree counters (stream-ordered, graph-capturable)
    hipMemsetAsync(bar, 0, 1024 * 18 * 4 + (size_t)n * 4, stream);

    k_mega<<<GRID, BLOCK, 0, stream>>>(
        gene, mask, W1, b1, W2, b2, Wd, bd, eidx_raw, perm_raw,
        bar, deg, eidx32, perm32, row_ptr, cursor, dinv, col, W1t, W2t,
        xw1, h_all, hw_all, x1_all, out_x1, out_ret1, out_ret1c, E, n);
}